// Round 1
// baseline (570.975 us; speedup 1.0000x reference)
//
#include <hip/hip_runtime.h>

#define NN 200000
#define DD 16
#define KK 16
#define FF 33   // 2*DD + 1

constexpr float EPSV  = 1e-5f;
constexpr float SLOPE = 0.2f;

__device__ __forceinline__ float leakyf(float v) {
    // for v>=0: 0.2v <= v -> max = v ; for v<0: 0.2v > v -> max = 0.2v
    return fmaxf(v, SLOPE * v);
}

__global__ __launch_bounds__(256) void dmasif_layer_kernel(
    const float* __restrict__ in,     // N x D  (previous layer output)
    float*       __restrict__ outp,   // N x D  (this layer output)
    const float* __restrict__ dists,  // N x K
    const int*   __restrict__ idx,    // N x K
    const float* __restrict__ W1,     // F x F  (this layer)
    const float* __restrict__ b1,     // F
    const float* __restrict__ W2,     // F x D
    const float* __restrict__ b2,     // D
    const float* __restrict__ gnw,    // D
    const float* __restrict__ gnb)    // D
{
    const int n = blockIdx.x * blockDim.x + threadIdx.x;
    if (n >= NN) return;

    // ---- load self features (64B coalesced) ----
    float self[DD];
    {
        const float4* sv = reinterpret_cast<const float4*>(in + (size_t)n * DD);
        float4 s0 = sv[0], s1 = sv[1], s2 = sv[2], s3 = sv[3];
        self[0]=s0.x; self[1]=s0.y; self[2]=s0.z; self[3]=s0.w;
        self[4]=s1.x; self[5]=s1.y; self[6]=s1.z; self[7]=s1.w;
        self[8]=s2.x; self[9]=s2.y; self[10]=s2.z; self[11]=s2.w;
        self[12]=s3.x; self[13]=s3.y; self[14]=s3.z; self[15]=s3.w;
    }

    // ---- base[g] = b1[g] + sum_d self[d] * W1[d][g]   (per-node, shared across k) ----
    float base[FF];
#pragma unroll
    for (int g = 0; g < FF; ++g) base[g] = b1[g];
#pragma unroll
    for (int dd = 0; dd < DD; ++dd) {
        const float s = self[dd];
#pragma unroll
        for (int g = 0; g < FF; ++g)
            base[g] = fmaf(s, W1[dd * FF + g], base[g]);
    }

    // ---- neighbor loop with 1-deep prefetch ----
    const int*   idxp = idx   + (size_t)n * KK;
    const float* dp   = dists + (size_t)n * KK;

    float hsum[FF];
#pragma unroll
    for (int g = 0; g < FF; ++g) hsum[g] = 0.0f;

    float4 pf0, pf1, pf2, pf3;
    {
        const int m0 = idxp[0];
        const float4* p = reinterpret_cast<const float4*>(in + (size_t)m0 * DD);
        pf0 = p[0]; pf1 = p[1]; pf2 = p[2]; pf3 = p[3];
    }

#pragma unroll 1
    for (int k = 0; k < KK; ++k) {
        // current neighbor features from prefetch regs (constant indices only)
        float nb[DD];
        nb[0]=pf0.x; nb[1]=pf0.y; nb[2]=pf0.z; nb[3]=pf0.w;
        nb[4]=pf1.x; nb[5]=pf1.y; nb[6]=pf1.z; nb[7]=pf1.w;
        nb[8]=pf2.x; nb[9]=pf2.y; nb[10]=pf2.z; nb[11]=pf2.w;
        nb[12]=pf3.x; nb[13]=pf3.y; nb[14]=pf3.z; nb[15]=pf3.w;

        const float dcur = dp[k];

        // issue next gather early so it hides under the FMA body
        if (k + 1 < KK) {
            const int mn = idxp[k + 1];
            const float4* p = reinterpret_cast<const float4*>(in + (size_t)mn * DD);
            pf0 = p[0]; pf1 = p[1]; pf2 = p[2]; pf3 = p[3];
        }

        // h[g] = base[g] + dcur * W1[32][g] + sum_d nb[d] * W1[16+d][g]
        float h[FF];
#pragma unroll
        for (int g = 0; g < FF; ++g)
            h[g] = fmaf(dcur, W1[(2 * DD) * FF + g], base[g]);
#pragma unroll
        for (int dd = 0; dd < DD; ++dd) {
            const float s = nb[dd];
#pragma unroll
            for (int g = 0; g < FF; ++g)
                h[g] = fmaf(s, W1[(DD + dd) * FF + g], h[g]);
        }
#pragma unroll
        for (int g = 0; g < FF; ++g)
            hsum[g] += leakyf(h[g]);
    }

    // ---- messages = hsum @ W2 + K*b2 ----
    float msg[DD];
#pragma unroll
    for (int d2 = 0; d2 < DD; ++d2) msg[d2] = (float)KK * b2[d2];
#pragma unroll
    for (int g = 0; g < FF; ++g) {
        const float s = hsum[g];
#pragma unroll
        for (int d2 = 0; d2 < DD; ++d2)
            msg[d2] = fmaf(s, W2[g * DD + d2], msg[d2]);
    }

    // ---- group norm (2 groups of 8) + leaky + residual ----
    float outv[DD];
#pragma unroll
    for (int grp = 0; grp < 2; ++grp) {
        float mu = 0.0f;
#pragma unroll
        for (int c = 0; c < 8; ++c) mu += msg[grp * 8 + c];
        mu *= 0.125f;
        float var = 0.0f;
#pragma unroll
        for (int c = 0; c < 8; ++c) {
            const float t = msg[grp * 8 + c] - mu;
            var = fmaf(t, t, var);
        }
        var *= 0.125f;
        const float rinv = rsqrtf(var + EPSV);
#pragma unroll
        for (int c = 0; c < 8; ++c) {
            const int ch = grp * 8 + c;
            const float xn = (msg[ch] - mu) * rinv;
            float yv = fmaf(xn, gnw[ch], gnb[ch]);
            yv = leakyf(yv);
            outv[ch] = self[ch] + yv;
        }
    }

    // ---- store (64B coalesced) ----
    float4* ov = reinterpret_cast<float4*>(outp + (size_t)n * DD);
    ov[0] = make_float4(outv[0],  outv[1],  outv[2],  outv[3]);
    ov[1] = make_float4(outv[4],  outv[5],  outv[6],  outv[7]);
    ov[2] = make_float4(outv[8],  outv[9],  outv[10], outv[11]);
    ov[3] = make_float4(outv[12], outv[13], outv[14], outv[15]);
}

extern "C" void kernel_launch(void* const* d_in, const int* in_sizes, int n_in,
                              void* d_out, int out_size, void* d_ws, size_t ws_size,
                              hipStream_t stream) {
    const float* y     = (const float*)d_in[0];   // N x D
    const float* dists = (const float*)d_in[1];   // N x K
    const float* W1    = (const float*)d_in[2];   // L x F x F
    const float* b1    = (const float*)d_in[3];   // L x F
    const float* W2    = (const float*)d_in[4];   // L x F x D
    const float* b2    = (const float*)d_in[5];   // L x D
    const float* gnw   = (const float*)d_in[6];   // L x D
    const float* gnb   = (const float*)d_in[7];   // L x D
    const int*   idx   = (const int*)d_in[8];     // N x K

    float* out  = (float*)d_out;
    float* buf0 = (float*)d_ws;                   // N x D scratch (12.8 MB)

    const int block = 256;
    const int grid  = (NN + block - 1) / block;

    // layer 0: y -> out ; layer 1: out -> buf0 ; layer 2: buf0 -> out
    // (gathers must read the PREVIOUS layer, so in-place is not allowed)
    dmasif_layer_kernel<<<grid, block, 0, stream>>>(
        y, out, dists, idx,
        W1 + 0 * FF * FF, b1 + 0 * FF, W2 + 0 * FF * DD, b2 + 0 * DD,
        gnw + 0 * DD, gnb + 0 * DD);

    dmasif_layer_kernel<<<grid, block, 0, stream>>>(
        out, buf0, dists, idx,
        W1 + 1 * FF * FF, b1 + 1 * FF, W2 + 1 * FF * DD, b2 + 1 * DD,
        gnw + 1 * DD, gnb + 1 * DD);

    dmasif_layer_kernel<<<grid, block, 0, stream>>>(
        buf0, out, dists, idx,
        W1 + 2 * FF * FF, b1 + 2 * FF, W2 + 2 * FF * DD, b2 + 2 * DD,
        gnw + 2 * DD, gnb + 2 * DD);
}